// Round 5
// baseline (178.946 us; speedup 1.0000x reference)
//
#include <hip/hip_runtime.h>
#include <hip/hip_bf16.h>
#include <string.h>

// ConvContract via bf16 MFMA implicit GEMM, async-staged.
// C[192 co][65536 px] = sum_k F[co][k] * X[k][px], k=(cin,tap), K=1728 (pad 2016).
// chunk = cin>>4 (12); kpos = tap*16 + cl, row padded to 168 (taps 9/10 zero).
// Xb[y][chunk][x][cl] bf16 (prep) ; Fb[chunk][co][168] bf16 (synth).
// out0 = C[0:64] + b0 ; out1 = C[64:192] + meanb  where
// meanb[c1] = b1[c1>>1] * sum_k F[64+c1][k] * meanX[cin(k)]   (torus-mean identity).

#define NN 256
#define NPIX 65536
#define OUT1_OFF 4194304
#define FS 168                 // padded F row stride (ushorts); 336B = 16B-aligned, 2-way banks

typedef __attribute__((ext_vector_type(8))) short short8;
typedef __attribute__((ext_vector_type(4))) float floatx4;

__device__ __forceinline__ unsigned short f2b(float x) {
    unsigned int u; memcpy(&u, &x, 4);
    return (unsigned short)((u + 0x7FFFu + ((u >> 16) & 1u)) >> 16);   // RTNE
}
__device__ __forceinline__ float b2f16(unsigned short u) {
    unsigned int v = ((unsigned int)u) << 16; float f; memcpy(&f, &v, 4); return f;
}
__device__ __forceinline__ unsigned int pack2(float a, float b) {
    return (unsigned int)f2b(a) | ((unsigned int)f2b(b) << 16);
}

// ----------------------------------------------------------------- prep ----
// grid (64 ygroup, 12 c), block 256 = 4 waves (wave -> y), lane tx -> cols 4tx..4tx+3.
// Writes Xb[y][c][x][cl] and partial[cin][y] = sum_x X[cin][y][x] (fp32).
__global__ __launch_bounds__(256) void prep_kernel(const float* __restrict__ x0,
                                                   const float* __restrict__ x1,
                                                   unsigned short* __restrict__ Xb,
                                                   float* __restrict__ partial) {
    const int t = threadIdx.x;
    const int w = t >> 6, tx = t & 63;
    const int y = blockIdx.x * 4 + w;
    const int c = blockIdx.y;
    const int col0 = tx * 4;

    unsigned int u[4][8];
    float sum[16];
    if (c < 4) {
        #pragma unroll
        for (int j = 0; j < 8; j++) {
            const float4 a = *(const float4*)(x0 + (size_t)(16 * c + 2 * j) * NPIX + y * NN + col0);
            const float4 b = *(const float4*)(x0 + (size_t)(16 * c + 2 * j + 1) * NPIX + y * NN + col0);
            u[0][j] = pack2(a.x, b.x);
            u[1][j] = pack2(a.y, b.y);
            u[2][j] = pack2(a.z, b.z);
            u[3][j] = pack2(a.w, b.w);
            sum[2 * j]     = a.x + a.y + a.z + a.w;
            sum[2 * j + 1] = b.x + b.y + b.z + b.w;
        }
    } else {
        #pragma unroll
        for (int j = 0; j < 8; j++) {
            int i = 8 * (c - 4) + j;
            const float* base = x1 + ((size_t)(i * 256 + y) * 256 + col0) * 2;
            const float4 p0 = *(const float4*)(base);      // cols col0,col0+1 (t=0,1)
            const float4 p1 = *(const float4*)(base + 4);  // cols col0+2,col0+3
            u[0][j] = pack2(p0.x, p0.y);
            u[1][j] = pack2(p0.z, p0.w);
            u[2][j] = pack2(p1.x, p1.y);
            u[3][j] = pack2(p1.z, p1.w);
            sum[2 * j]     = p0.x + p0.z + p1.x + p1.z;
            sum[2 * j + 1] = p0.y + p0.w + p1.y + p1.w;
        }
    }
    uint4* dst = (uint4*)(Xb + (((size_t)y * 12 + c) * 256 + col0) * 16);
    #pragma unroll
    for (int cc = 0; cc < 4; cc++) {
        dst[cc * 2]     = make_uint4(u[cc][0], u[cc][1], u[cc][2], u[cc][3]);
        dst[cc * 2 + 1] = make_uint4(u[cc][4], u[cc][5], u[cc][6], u[cc][7]);
    }
    #pragma unroll
    for (int cl = 0; cl < 16; cl++)
        #pragma unroll
        for (int d = 1; d < 64; d <<= 1) sum[cl] += __shfl_xor(sum[cl], d, 64);
    if (tx < 16) partial[(c * 16 + tx) * 256 + y] = sum[tx];
}

// ---------------------------------------------------------------- synth ----
// Fb[c][co][kpos] bf16, kpos in [0,168); zero for tap >= 9.
__global__ void synth_kernel(const float* __restrict__ fil0, const float* __restrict__ fil1,
                             const float* __restrict__ fil2,
                             const float* __restrict__ w00, const float* __restrict__ w01,
                             const float* __restrict__ w10, const float* __restrict__ w11,
                             unsigned short* __restrict__ Fb) {
    int idx = blockIdx.x * 256 + threadIdx.x;
    if (idx >= 12 * 192 * FS) return;
    int kpos = idx % FS;
    int co   = (idx / FS) % 192;
    int c    = idx / (FS * 192);
    int tap = kpos >> 4, cl = kpos & 15;
    float s = 0.0f;
    if (tap < 9) {
        int cin = c * 16 + cl;
        if (co < 64) {
            if (cin < 64) {
                for (int k = 0; k < 3; k++)
                    s += w00[(co * 64 + cin) * 3 + k] * fil0[k * 9 + tap];
            } else {
                int i = (cin - 64) >> 1, t = (cin - 64) & 1;
                for (int k = 0; k < 6; k++)
                    s += w10[(co * 64 + i) * 6 + k] * fil1[(k * 9 + tap) * 2 + t];
            }
        } else {
            int o = (co - 64) >> 1, u = (co - 64) & 1;
            if (cin < 64) {
                for (int k = 0; k < 6; k++)
                    s += w01[(o * 64 + cin) * 6 + k] * fil1[(k * 9 + tap) * 2 + u];
            } else {
                int i = (cin - 64) >> 1, t = (cin - 64) & 1;
                for (int k = 0; k < 12; k++)
                    s += w11[(o * 64 + i) * 12 + k] * fil2[((k * 9 + tap) * 2 + t) * 2 + u];
            }
        }
    }
    Fb[idx] = f2b(s);
}

// ---------------------------------------------------------------- meanX ----
// meanX[cin] = (sum_y partial[cin][y]) / 65536 ; grid 3, block 64.
__global__ void meanx_kernel(const float* __restrict__ partial, float* __restrict__ meanX) {
    int cin = blockIdx.x * 64 + threadIdx.x;
    const float4* p = (const float4*)(partial + (size_t)cin * 256);
    float s = 0.0f;
    for (int j = 0; j < 64; j++) { float4 v = p[j]; s += v.x + v.y + v.z + v.w; }
    meanX[cin] = s * (1.0f / 65536.0f);
}

// ---------------------------------------------------------------- meanb ----
// meanb[c1] = b1[c1>>1] * sum_{c,tap,cl} Fb[c][64+c1][tap*16+cl] * meanX[16c+cl].
__global__ void meanb_kernel(const unsigned short* __restrict__ Fb,
                             const float* __restrict__ meanX,
                             const float* __restrict__ b1, float* __restrict__ meanb) {
    int c1 = blockIdx.x;            // 128
    int l = threadIdx.x;            // 64
    int co = 64 + c1;
    float s = 0.0f;
    for (int c = 0; c < 12; c++) {
        const unsigned short* row = Fb + ((size_t)c * 192 + co) * FS;
        for (int idx = l; idx < 144; idx += 64) {
            int tap = idx >> 4, cl = idx & 15;
            s += b2f16(row[tap * 16 + cl]) * meanX[c * 16 + cl];
        }
    }
    #pragma unroll
    for (int d = 1; d < 64; d <<= 1) s += __shfl_xor(s, d, 64);
    if (l == 0) meanb[c1] = s * b1[c1 >> 1];
}

// ----------------------------------------------------------------- conv ----
// grid (256 y, 2 mtile), block 512 = 8 waves (2 wm x 4 wn); wave tile 48M x 64N.
__global__ __launch_bounds__(512, 4) void conv_kernel(
    const unsigned short* __restrict__ Xb, const unsigned short* __restrict__ Fb,
    const float* __restrict__ b0, const float* __restrict__ meanb,
    float* __restrict__ out) {

    __shared__ __align__(16) unsigned short Flds[16384];      // 96*168 = 16128 used (+overrun pad)
    __shared__ __align__(16) unsigned short Xlds[3 * 256 * 16]; // 24576 B

    const int tid = threadIdx.x;
    const int y = blockIdx.x;
    const int m0 = blockIdx.y * 96;
    const int l = tid & 63, w = tid >> 6;
    const int wm = w >> 2, wn = w & 3;
    const int mw = wm * 48, nw = wn * 64;
    const int ln = l & 15, quad = l >> 4;

    int baseA[3];
#pragma unroll
    for (int f = 0; f < 3; f++) baseA[f] = (mw + f * 16 + ln) * FS + quad * 8;
    int cb[4];
#pragma unroll
    for (int g = 0; g < 4; g++) cb[g] = nw + g * 16 + ln;
    int rofs[5], dxv[5];
#pragma unroll
    for (int ks = 0; ks < 5; ks++) {
        int tap = 2 * ks + (quad >> 1);
        int r, dx;
        if (tap > 8) { r = 0; dx = 0; }            // pad tap: F=0, address harmless
        else { r = tap / 3; dx = tap - 3 * r - 1; }
        rofs[ks] = r * 4096 + (quad & 1) * 8;
        dxv[ks] = dx;
    }

    floatx4 acc[3][4];
#pragma unroll
    for (int f = 0; f < 3; f++)
#pragma unroll
        for (int g = 0; g < 4; g++) acc[f][g] = (floatx4){0.f, 0.f, 0.f, 0.f};

    for (int c = 0; c < 12; c++) {
        // ---- async stage: F (32 segs x 1KB, 512B overrun into pad) + X (24 segs) ----
        const unsigned short* FbC = Fb + ((size_t)c * 192 + m0) * FS;
        for (int s = w; s < 56; s += 8) {
            const unsigned short* g;
            unsigned short* lb;
            if (s < 32) {
                g = FbC + s * 512;
                lb = Flds + s * 512;
            } else {
                int j = s - 32;
                int r = j >> 3, p = j & 7;
                int yr = (y + r + 255) & 255;
                g = Xb + (((size_t)yr * 12 + c) * 4096) + p * 512;
                lb = Xlds + r * 4096 + p * 512;
            }
            __builtin_amdgcn_global_load_lds(
                (const __attribute__((address_space(1))) unsigned int*)(g + l * 8),
                (__attribute__((address_space(3))) unsigned int*)lb, 16, 0, 0);
        }
        __syncthreads();

        // ---- compute: 5 K32 steps x (3 A x 4 B) ----
#pragma unroll
        for (int ks = 0; ks < 5; ks++) {
            short8 A[3], B[4];
#pragma unroll
            for (int f = 0; f < 3; f++)
                A[f] = *(const short8*)(Flds + baseA[f] + ks * 32);
#pragma unroll
            for (int g = 0; g < 4; g++) {
                int colw = (cb[g] + dxv[ks]) & 255;
                B[g] = *(const short8*)(Xlds + rofs[ks] + colw * 16);
            }
#pragma unroll
            for (int f = 0; f < 3; f++)
#pragma unroll
                for (int g = 0; g < 4; g++)
                    acc[f][g] = __builtin_amdgcn_mfma_f32_16x16x32_bf16(A[f], B[g], acc[f][g], 0, 0, 0);
        }
        __syncthreads();
    }

    // ------------------------------------------------------- epilogue ----
    // C/D layout: col = ln, row(within 16) = quad*4 + reg.
#pragma unroll
    for (int f = 0; f < 3; f++) {
        int cob = m0 + mw + f * 16 + quad * 4;
#pragma unroll
        for (int g = 0; g < 4; g++) {
            int col = nw + g * 16 + ln;
            if (cob < 64) {
#pragma unroll
                for (int reg = 0; reg < 4; reg++)
                    out[(size_t)(cob + reg) * NPIX + y * NN + col] = acc[f][g][reg] + b0[cob + reg];
            } else {
#pragma unroll
                for (int reg = 0; reg < 4; reg += 2) {
                    int c1 = cob + reg - 64;
                    int o = c1 >> 1;
                    float2 v = make_float2(acc[f][g][reg] + meanb[c1],
                                           acc[f][g][reg + 1] + meanb[c1 + 1]);
                    *((float2*)(out + OUT1_OFF) + ((size_t)o * NPIX + y * NN + col)) = v;
                }
            }
        }
    }
}

// --------------------------------------------------------------- launch ----
extern "C" void kernel_launch(void* const* d_in, const int* in_sizes, int n_in,
                              void* d_out, int out_size, void* d_ws, size_t ws_size,
                              hipStream_t stream) {
    const float* x0   = (const float*)d_in[0];
    const float* x1   = (const float*)d_in[1];
    const float* fil0 = (const float*)d_in[2];
    const float* fil1 = (const float*)d_in[3];
    const float* fil2 = (const float*)d_in[4];
    const float* w00  = (const float*)d_in[5];
    const float* w01  = (const float*)d_in[6];
    const float* w10  = (const float*)d_in[7];
    const float* w11  = (const float*)d_in[8];
    const float* b0   = (const float*)d_in[9];
    const float* b1   = (const float*)d_in[10];

    unsigned short* Xb = (unsigned short*)d_ws;                       // 25,165,824 B
    unsigned short* Fb = (unsigned short*)((char*)d_ws + 25165824);   //    774,144 B (+512 slack)
    float* partial     = (float*)((char*)d_ws + 25940480);            //    196,608 B
    float* meanX       = (float*)((char*)d_ws + 26137088);            //        768 B
    float* meanb       = (float*)((char*)d_ws + 26138112);            //        512 B
    float* out = (float*)d_out;

    prep_kernel<<<dim3(64, 12), 256, 0, stream>>>(x0, x1, Xb, partial);

    synth_kernel<<<(12 * 192 * FS + 255) / 256, 256, 0, stream>>>(
        fil0, fil1, fil2, w00, w01, w10, w11, Fb);

    meanx_kernel<<<3, 64, 0, stream>>>(partial, meanX);

    meanb_kernel<<<128, 64, 0, stream>>>(Fb, meanX, b1, meanb);

    conv_kernel<<<dim3(NN, 2), 512, 0, stream>>>(Xb, Fb, b0, meanb, out);
}

// Round 7
// 171.756 us; speedup vs baseline: 1.0419x; 1.0419x over previous
//
#include <hip/hip_runtime.h>
#include <hip/hip_bf16.h>
#include <string.h>

// ConvContract via bf16 MFMA implicit GEMM, async-staged. 4 kernels:
// prep:   Xb[y][c][x][cl] = bf16(X[cin][y][x]) ; partial[cin][y] = row sums.
// synth:  Fb[c][co][kpos] bf16, kpos = tap*16+cl (tap 9 = zero pad), FS=160.
// meanbx: meanb[c1] = b1[c1>>1] * sum_k F[64+c1][k] * meanX[cin(k)]  (torus identity:
//         spatial mean of a torus conv = (sum of taps) . (channel means), exact).
// conv:   C[192][65536] = sum_k F*X via MFMA 16x16x32; out0=C[0:64]+b0,
//         out1=C[64:192]+meanb fused in epilogue.

#define NN 256
#define NPIX 65536
#define OUT1_OFF 4194304
#define FS 160                 // F row stride (10 taps x 16 cl; tap 9 zero)

typedef __attribute__((ext_vector_type(8))) short short8;
typedef __attribute__((ext_vector_type(4))) float floatx4;

__device__ __forceinline__ unsigned short f2b(float x) {
    unsigned int u; memcpy(&u, &x, 4);
    return (unsigned short)((u + 0x7FFFu + ((u >> 16) & 1u)) >> 16);   // RTNE
}
__device__ __forceinline__ float b2f16(unsigned short u) {
    unsigned int v = ((unsigned int)u) << 16; float f; memcpy(&f, &v, 4); return f;
}
__device__ __forceinline__ unsigned int pack2(float a, float b) {
    return (unsigned int)f2b(a) | ((unsigned int)f2b(b) << 16);
}

// ----------------------------------------------------------------- prep ----
// grid (64 ygroup, 12 c), block 256 = 4 waves (wave -> y), lane tx -> cols 4tx..4tx+3.
__global__ __launch_bounds__(256) void prep_kernel(const float* __restrict__ x0,
                                                   const float* __restrict__ x1,
                                                   unsigned short* __restrict__ Xb,
                                                   float* __restrict__ partial) {
    const int t = threadIdx.x;
    const int w = t >> 6, tx = t & 63;
    const int y = blockIdx.x * 4 + w;
    const int c = blockIdx.y;
    const int col0 = tx * 4;

    unsigned int u[4][8];
    float sum[16];
    if (c < 4) {
        #pragma unroll
        for (int j = 0; j < 8; j++) {
            const float4 a = *(const float4*)(x0 + (size_t)(16 * c + 2 * j) * NPIX + y * NN + col0);
            const float4 b = *(const float4*)(x0 + (size_t)(16 * c + 2 * j + 1) * NPIX + y * NN + col0);
            u[0][j] = pack2(a.x, b.x);
            u[1][j] = pack2(a.y, b.y);
            u[2][j] = pack2(a.z, b.z);
            u[3][j] = pack2(a.w, b.w);
            sum[2 * j]     = a.x + a.y + a.z + a.w;
            sum[2 * j + 1] = b.x + b.y + b.z + b.w;
        }
    } else {
        #pragma unroll
        for (int j = 0; j < 8; j++) {
            int i = 8 * (c - 4) + j;
            const float* base = x1 + ((size_t)(i * 256 + y) * 256 + col0) * 2;
            const float4 p0 = *(const float4*)(base);
            const float4 p1 = *(const float4*)(base + 4);
            u[0][j] = pack2(p0.x, p0.y);
            u[1][j] = pack2(p0.z, p0.w);
            u[2][j] = pack2(p1.x, p1.y);
            u[3][j] = pack2(p1.z, p1.w);
            sum[2 * j]     = p0.x + p0.z + p1.x + p1.z;
            sum[2 * j + 1] = p0.y + p0.w + p1.y + p1.w;
        }
    }
    uint4* dst = (uint4*)(Xb + (((size_t)y * 12 + c) * 256 + col0) * 16);
    #pragma unroll
    for (int cc = 0; cc < 4; cc++) {
        dst[cc * 2]     = make_uint4(u[cc][0], u[cc][1], u[cc][2], u[cc][3]);
        dst[cc * 2 + 1] = make_uint4(u[cc][4], u[cc][5], u[cc][6], u[cc][7]);
    }
    #pragma unroll
    for (int cl = 0; cl < 16; cl++)
        #pragma unroll
        for (int d = 1; d < 64; d <<= 1) sum[cl] += __shfl_xor(sum[cl], d, 64);
    if (tx < 16) partial[(c * 16 + tx) * 256 + y] = sum[tx];
}

// ---------------------------------------------------------------- synth ----
__global__ void synth_kernel(const float* __restrict__ fil0, const float* __restrict__ fil1,
                             const float* __restrict__ fil2,
                             const float* __restrict__ w00, const float* __restrict__ w01,
                             const float* __restrict__ w10, const float* __restrict__ w11,
                             unsigned short* __restrict__ Fb) {
    int idx = blockIdx.x * 256 + threadIdx.x;
    if (idx >= 12 * 192 * FS) return;
    int kpos = idx % FS;
    int co   = (idx / FS) % 192;
    int c    = idx / (FS * 192);
    int tap = kpos >> 4, cl = kpos & 15;
    float s = 0.0f;
    if (tap < 9) {
        int cin = c * 16 + cl;
        if (co < 64) {
            if (cin < 64) {
                for (int k = 0; k < 3; k++)
                    s += w00[(co * 64 + cin) * 3 + k] * fil0[k * 9 + tap];
            } else {
                int i = (cin - 64) >> 1, t = (cin - 64) & 1;
                for (int k = 0; k < 6; k++)
                    s += w10[(co * 64 + i) * 6 + k] * fil1[(k * 9 + tap) * 2 + t];
            }
        } else {
            int o = (co - 64) >> 1, u = (co - 64) & 1;
            if (cin < 64) {
                for (int k = 0; k < 6; k++)
                    s += w01[(o * 64 + cin) * 6 + k] * fil1[(k * 9 + tap) * 2 + u];
            } else {
                int i = (cin - 64) >> 1, t = (cin - 64) & 1;
                for (int k = 0; k < 12; k++)
                    s += w11[(o * 64 + i) * 12 + k] * fil2[((k * 9 + tap) * 2 + t) * 2 + u];
            }
        }
    }
    Fb[idx] = f2b(s);
}

// --------------------------------------------------------------- meanbx ----
// grid 128 (c1), block 256. Each block recomputes meanX (L2-resident partial).
__global__ void meanbx_kernel(const unsigned short* __restrict__ Fb,
                              const float* __restrict__ partial,
                              const float* __restrict__ b1, float* __restrict__ meanb) {
    __shared__ float mX[192];
    __shared__ float rd[4];
    const int c1 = blockIdx.x;
    const int t = threadIdx.x;
    if (t < 192) {
        const float4* p = (const float4*)(partial + (size_t)t * 256);
        float s = 0.0f;
        for (int j = 0; j < 64; j++) { float4 v = p[j]; s += v.x + v.y + v.z + v.w; }
        mX[t] = s * (1.0f / 65536.0f);
    }
    __syncthreads();
    float s = 0.0f;
    for (int e = t; e < 1728; e += 256) {
        int c = e / 144, r = e - c * 144;
        int tap = r >> 4, cl = r & 15;
        s += b2f16(Fb[((size_t)c * 192 + 64 + c1) * FS + tap * 16 + cl]) * mX[c * 16 + cl];
    }
#pragma unroll
    for (int d = 1; d < 64; d <<= 1) s += __shfl_xor(s, d, 64);
    if ((t & 63) == 0) rd[t >> 6] = s;
    __syncthreads();
    if (t == 0) meanb[c1] = (rd[0] + rd[1] + rd[2] + rd[3]) * b1[c1 >> 1];
}

// ----------------------------------------------------------------- conv ----
// grid (256 y, 2 mtile), block 512 = 8 waves (2 wm x 4 wn); wave tile 48M x 64N.
__global__ __launch_bounds__(512, 4) void conv_kernel(
    const unsigned short* __restrict__ Xb, const unsigned short* __restrict__ Fb,
    const float* __restrict__ b0, const float* __restrict__ meanb,
    float* __restrict__ out) {

    __shared__ __align__(16) unsigned short Flds[96 * FS];      // 30720 B
    __shared__ __align__(16) unsigned short Xlds[3 * 256 * 16]; // 24576 B

    const int tid = threadIdx.x;
    const int y = blockIdx.x;
    const int m0 = blockIdx.y * 96;
    const int l = tid & 63, w = tid >> 6;
    const int wm = w >> 2, wn = w & 3;
    const int mw = wm * 48, nw = wn * 64;
    const int ln = l & 15, quad = l >> 4;

    int baseA[3];
#pragma unroll
    for (int f = 0; f < 3; f++) baseA[f] = (mw + f * 16 + ln) * FS + quad * 8;
    int cb[4];
#pragma unroll
    for (int g = 0; g < 4; g++) cb[g] = nw + g * 16 + ln;
    int rofs[5], dxv[5];
#pragma unroll
    for (int ks = 0; ks < 5; ks++) {
        int tap = 2 * ks + (quad >> 1);
        int r, dx;
        if (tap > 8) { r = 0; dx = 0; }            // zero-pad tap: F=0, address harmless
        else { r = tap / 3; dx = tap - 3 * r - 1; }
        rofs[ks] = r * 4096 + (quad & 1) * 8;
        dxv[ks] = dx;
    }

    floatx4 acc[3][4];
#pragma unroll
    for (int f = 0; f < 3; f++)
#pragma unroll
        for (int g = 0; g < 4; g++) acc[f][g] = (floatx4){0.f, 0.f, 0.f, 0.f};

    for (int c = 0; c < 12; c++) {
        // ---- async stage: F (30 segs x 1KB) + X (24 segs x 1KB) ----
        const unsigned short* FbC = Fb + ((size_t)c * 192 + m0) * FS;
        for (int s = w; s < 54; s += 8) {
            const unsigned short* g;
            unsigned short* lb;
            if (s < 30) {
                g = FbC + s * 512;
                lb = Flds + s * 512;
            } else {
                int j = s - 30;
                int r = j >> 3, p = j & 7;
                int yr = (y + r + 255) & 255;
                g = Xb + (((size_t)yr * 12 + c) * 4096) + p * 512;
                lb = Xlds + r * 4096 + p * 512;
            }
            __builtin_amdgcn_global_load_lds(
                (const __attribute__((address_space(1))) unsigned int*)(g + l * 8),
                (__attribute__((address_space(3))) unsigned int*)lb, 16, 0, 0);
        }
        __syncthreads();

        // ---- compute: 5 K32 steps x (3 A x 4 B) ----
#pragma unroll
        for (int ks = 0; ks < 5; ks++) {
            short8 A[3], B[4];
#pragma unroll
            for (int f = 0; f < 3; f++)
                A[f] = *(const short8*)(Flds + baseA[f] + ks * 32);
#pragma unroll
            for (int g = 0; g < 4; g++) {
                int colw = (cb[g] + dxv[ks]) & 255;
                B[g] = *(const short8*)(Xlds + rofs[ks] + colw * 16);
            }
#pragma unroll
            for (int f = 0; f < 3; f++)
#pragma unroll
                for (int g = 0; g < 4; g++)
                    acc[f][g] = __builtin_amdgcn_mfma_f32_16x16x32_bf16(A[f], B[g], acc[f][g], 0, 0, 0);
        }
        __syncthreads();
    }

    // ------------------------------------------------------- epilogue ----
    // C/D layout: col = ln, row(within 16) = quad*4 + reg.
#pragma unroll
    for (int f = 0; f < 3; f++) {
        int cob = m0 + mw + f * 16 + quad * 4;
#pragma unroll
        for (int g = 0; g < 4; g++) {
            int col = nw + g * 16 + ln;
            if (cob < 64) {
#pragma unroll
                for (int reg = 0; reg < 4; reg++)
                    out[(size_t)(cob + reg) * NPIX + y * NN + col] = acc[f][g][reg] + b0[cob + reg];
            } else {
#pragma unroll
                for (int reg = 0; reg < 4; reg += 2) {
                    int c1 = cob + reg - 64;
                    int o = c1 >> 1;
                    float2 v = make_float2(acc[f][g][reg] + meanb[c1],
                                           acc[f][g][reg + 1] + meanb[c1 + 1]);
                    *((float2*)(out + OUT1_OFF) + ((size_t)o * NPIX + y * NN + col)) = v;
                }
            }
        }
    }
}

// --------------------------------------------------------------- launch ----
extern "C" void kernel_launch(void* const* d_in, const int* in_sizes, int n_in,
                              void* d_out, int out_size, void* d_ws, size_t ws_size,
                              hipStream_t stream) {
    const float* x0   = (const float*)d_in[0];
    const float* x1   = (const float*)d_in[1];
    const float* fil0 = (const float*)d_in[2];
    const float* fil1 = (const float*)d_in[3];
    const float* fil2 = (const float*)d_in[4];
    const float* w00  = (const float*)d_in[5];
    const float* w01  = (const float*)d_in[6];
    const float* w10  = (const float*)d_in[7];
    const float* w11  = (const float*)d_in[8];
    const float* b0   = (const float*)d_in[9];
    const float* b1   = (const float*)d_in[10];

    unsigned short* Xb = (unsigned short*)d_ws;                       // 25,165,824 B
    unsigned short* Fb = (unsigned short*)((char*)d_ws + 25165824);   //    737,280 B
    float* partial     = (float*)((char*)d_ws + 25903104);            //    196,608 B
    float* meanb       = (float*)((char*)d_ws + 26099712);            //        512 B
    float* out = (float*)d_out;

    prep_kernel<<<dim3(64, 12), 256, 0, stream>>>(x0, x1, Xb, partial);

    synth_kernel<<<(12 * 192 * FS + 255) / 256, 256, 0, stream>>>(
        fil0, fil1, fil2, w00, w01, w10, w11, Fb);

    meanbx_kernel<<<128, 256, 0, stream>>>(Fb, partial, b1, meanb);

    conv_kernel<<<dim3(NN, 2), 512, 0, stream>>>(Xb, Fb, b0, meanb, out);
}